// Round 10
// baseline (141.536 us; speedup 1.0000x reference)
//
#include <hip/hip_runtime.h>

// Problem constants: x [4, 64, 64, 128] fp32
constexpr int C       = 128;
constexpr int N       = 4096;
constexpr int BATCH   = 4;
constexpr int TOTROWS = BATCH * N;            // 16384
constexpr float SCALE = 0.08838834764831845f; // 1/sqrt(128)
constexpr float LOG2E = 1.44269504088896340736f;

constexpr int BK  = 64;    // keys per iteration
constexpr int PST = 36;    // P-tile row stride in shorts (72B: bank-minimal)

typedef __attribute__((ext_vector_type(8))) short        bf16x8;
typedef __attribute__((ext_vector_type(4))) float        f32x4;
typedef __attribute__((ext_vector_type(2))) unsigned int u32x2;

__device__ inline unsigned short f2bf(float f) {   // RNE float->bf16 (scalar)
    unsigned int u = __float_as_uint(f);
    return (unsigned short)((u + 0x7FFFu + ((u >> 16) & 1u)) >> 16);
}
// packed RNE f32x2 -> bf16x2 in ONE instruction
__device__ inline unsigned int cvtpk(float a, float b) {
    unsigned int r;
    asm("v_cvt_pk_bf16_f32 %0, %1, %2" : "=v"(r) : "v"(a), "v"(b));
    return r;
}
__device__ inline float bf2f(unsigned int u) {
    return __uint_as_float(u << 16);
}
// bare v_exp_f32 (q is pre-scaled by LOG2E; no OCML range-fixup needed)
__device__ inline float fexp2(float x) {
#if __has_builtin(__builtin_amdgcn_exp2f)
    return __builtin_amdgcn_exp2f(x);
#else
    float r; asm("v_exp_f32 %0, %1\n\ts_nop 0" : "=v"(r) : "v"(x)); return r;
#endif
}
// async global->LDS DMA, 16B per lane; LDS dest = wave-uniform base + lane*16
__device__ inline void dma16(const void* g, void* l) {
    __builtin_amdgcn_global_load_lds(
        (const __attribute__((address_space(1))) void*)g,
        (__attribute__((address_space(3))) void*)l, 16, 0, 0);
}

// ---------------------------------------------------------------------------
// wprep (r8-verified): one-time W transpose (3 blocks x 256 thr), contiguous
// 16B stores. granule g of row o holds W[i][o], i = ((g&8)|((g&7)^xr))*8+e,
// xr=(o>>2)&7 — the exact swizzled LDS image qkv's MFMA reads expect.
// ---------------------------------------------------------------------------
__global__ __launch_bounds__(256)
void wprep_kernel(const float* __restrict__ Wq, const float* __restrict__ Wk,
                  const float* __restrict__ Wv, unsigned short* __restrict__ wt)
{
    const int mat = blockIdx.x;
    const float* W = (mat == 0) ? Wq : (mat == 1) ? Wk : Wv;
    const float  s = (mat == 0) ? SCALE * LOG2E : 1.0f;
    unsigned short* dst = wt + mat * 16384;

    const int t  = threadIdx.x;
    const int o  = t >> 1;             // output chan (W^T row), 0..127
    const int g0 = (t & 1) * 8;        // granule half
    const int xr = (o >> 2) & 7;
    #pragma unroll
    for (int gg = 0; gg < 8; ++gg) {
        const int g   = g0 + gg;
        const int ihi = (g & 8) | ((g & 7) ^ xr);
        const int i0  = ihi << 3;
        union { unsigned short u16[8]; uint4 v; } buf;
        #pragma unroll
        for (int e = 0; e < 8; ++e)
            buf.u16[e] = f2bf(W[(i0 + e) * 128 + o] * s);
        *reinterpret_cast<uint4*>(&dst[o * 128 + g * 8]) = buf.v;
    }
}

// ---------------------------------------------------------------------------
// qkv (r9-verified): grid (TOTROWS/64, 3) = 768 blocks; W-image DMA issued
// before the x loads; single barrier; verified epilogues.
// ---------------------------------------------------------------------------
__global__ __launch_bounds__(256, 2)
void qkv_kernel(const float* __restrict__ x, const unsigned short* __restrict__ wt,
                const float* __restrict__ bq, const float* __restrict__ bk,
                const float* __restrict__ bv,
                unsigned short* __restrict__ qo,
                unsigned short* __restrict__ ko,
                unsigned short* __restrict__ vt)
{
    __shared__ __align__(16) unsigned short wl[16384];   // 32768 B

    const int tid  = threadIdx.x;
    const int lane = tid & 63;
    const int lo   = lane & 15;
    const int quad = lane >> 4;
    const int mat  = blockIdx.y;
    const long rowbase = (long)blockIdx.x * 64 + (tid >> 6) * 16;

    // issue W-image DMA first: latency hides under the x loads below
    {
        const char* src = (const char*)(wt + mat * 16384);
        #pragma unroll
        for (int c = 0; c < 8; ++c)
            dma16(src + (c * 256 + tid) * 16, &wl[(c * 256 + tid) * 8]);
    }

    // x fragments (row = rowbase+lo, k = ks*32+quad*8), fp32->bf16 in regs.
    bf16x8 xf[4];
    {
        const float4* xr = reinterpret_cast<const float4*>(&x[(rowbase + lo) * C]);
        #pragma unroll
        for (int ks = 0; ks < 4; ++ks) {
            float4 a  = xr[ks * 8 + quad * 2];
            float4 b2 = xr[ks * 8 + quad * 2 + 1];
            union { bf16x8 v; unsigned int u[4]; } cv;
            cv.u[0] = cvtpk(a.x, a.y);
            cv.u[1] = cvtpk(a.z, a.w);
            cv.u[2] = cvtpk(b2.x, b2.y);
            cv.u[3] = cvtpk(b2.z, b2.w);
            xf[ks] = cv.v;
        }
    }

    __syncthreads();                  // drains DMA (vmcnt 0)

    if (mat < 2) {
        // q/k: D[m=outchan][n=row], A=W^T frag, B=xf -> row-major store
        f32x4 acc[8] = {};
        #pragma unroll
        for (int ks = 0; ks < 4; ++ks)
            #pragma unroll
            for (int mt = 0; mt < 8; ++mt) {
                const int rr = mt * 16 + lo;
                bf16x8 wf = *reinterpret_cast<const bf16x8*>(
                    &wl[rr * 128 + (((ks * 4 + quad) ^ ((rr >> 2) & 7)) << 3)]);
                acc[mt] = __builtin_amdgcn_mfma_f32_16x16x32_bf16(
                    wf, xf[ks], acc[mt], 0, 0, 0);
            }
        const float* bias = (mat == 0) ? bq : bk;
        const float  s    = (mat == 0) ? SCALE * LOG2E : 1.0f;
        unsigned short* out = (mat == 0) ? qo : ko;
        long row = rowbase + lo;
        #pragma unroll
        for (int mt = 0; mt < 8; ++mt) {
            float4 bb = *reinterpret_cast<const float4*>(&bias[mt * 16 + quad * 4]);
            u32x2 w;
            w[0] = cvtpk(acc[mt][0] + bb.x * s, acc[mt][1] + bb.y * s);
            w[1] = cvtpk(acc[mt][2] + bb.z * s, acc[mt][3] + bb.w * s);
            *reinterpret_cast<u32x2*>(&out[row * C + mt * 16 + quad * 4]) = w;
        }
    } else {
        // v: D[m=row][n=chan], A=xf, B=W^T frag -> tiled transposed store
        f32x4 acc[8] = {};
        #pragma unroll
        for (int ks = 0; ks < 4; ++ks)
            #pragma unroll
            for (int ct = 0; ct < 8; ++ct) {
                const int rr = ct * 16 + lo;
                bf16x8 wf = *reinterpret_cast<const bf16x8*>(
                    &wl[rr * 128 + (((ks * 4 + quad) ^ ((rr >> 2) & 7)) << 3)]);
                acc[ct] = __builtin_amdgcn_mfma_f32_16x16x32_bf16(
                    xf[ks], wf, acc[ct], 0, 0, 0);
            }
        const int b = (int)(rowbase >> 12);
        const int nbase = (int)(rowbase & (N - 1));
        const int n0   = nbase + quad * 4;
        const int nblk = n0 >> 6;
        #pragma unroll
        for (int ct = 0; ct < 8; ++ct) {
            int chan = ct * 16 + lo;
            float bb = bv[chan];
            u32x2 w;
            w[0] = cvtpk(acc[ct][0] + bb, acc[ct][1] + bb);
            w[1] = cvtpk(acc[ct][2] + bb, acc[ct][3] + bb);
            *reinterpret_cast<u32x2*>(
                &vt[(((size_t)b * 64 + nblk) * 128 + chan) * 64 + (n0 & 63)]) = w;
        }
    }
}

// ---------------------------------------------------------------------------
// Flash attention, round-23: r3-verified body + P-TILE BANK FIX + setprio.
// r9 audit: SQ_LDS_BANK_CONFLICT 5.9M/dispatch ~= 20% of kernel cycles.
// K/V read patterns are bank-minimal (verified lane-by-lane), but the P tile
// (rows = 32 shorts = 64B) collapses 16 lanes onto 2 bank-cosets: 4-way
// conflicts on EVERY P write and read. Fix: row stride 36 shorts (72B pad),
// XOR dropped — prow*18 mod 32 covers all 16 even banks; both the b64
// writes (4-cycle) and b128 reads (8-cycle) now hit the theoretical minimum.
// Op ORDER is byte-identical to the verified r3 body (addresses only).
// T5: s_setprio(1) wraps the QK and PV MFMA clusters (isolated here on a
// verified base; 2 independent blocks/CU give the phase diversity it needs).
// LDS: 34944 + 32768 + 9216 = 76,928 B -> 2 blocks/CU.
// ---------------------------------------------------------------------------
__global__ __launch_bounds__(256, 2)
void attn_kernel(const unsigned short* __restrict__ q,
                 const unsigned short* __restrict__ k,
                 const unsigned short* __restrict__ vt,
                 unsigned short* __restrict__ opart,
                 float* __restrict__ lpart)
{
    // buffer A: K0 @0 (8192), V0 @8192 (8192), pad to 17472 shorts;
    //           reused as O-bounce (128 x 136 shorts) in the epilogue
    __shared__ __align__(16) unsigned short smA[17472];  // 34944 B
    __shared__ __align__(16) unsigned short smB[16384];  // 32768 B (K1,V1)
    __shared__ __align__(16) unsigned short smP[4608];   //  9216 B (4 x 32 x PST)

    const int tid  = threadIdx.x;
    const int wv   = tid >> 6;          // 0..3
    const int lane = tid & 63;
    const int lo   = lane & 15;
    const int quad = lane >> 4;

    const int nspl = (int)(gridDim.x >> 7);      // 512 -> 4, 256 -> 2
    const int id   = blockIdx.x;
    int b, sl, qt;
    if (nspl == 4) {         // id%8 = b*2 + (sl&1): pins (batch,parity) to XCD
        b  = (id >> 1) & 3;
        sl = (id & 1) | (((id >> 3) & 1) << 1);
        qt = id >> 4;        // 0..31
    } else {
        b  = (id >> 1) & 3;
        sl = id & 1;
        qt = id >> 3;
    }
    const int NIT  = (N / nspl) / BK;            // 16 (nspl=4), even
    const int koff = sl * (N / nspl);

    const int    rowb  = b * N + qt * 128;       // block's first q-row (global)
    const size_t qrow0 = (size_t)rowb + wv * 32; // wave's first q-row
    const char* kb8 = (const char*)(k  + ((size_t)b * N + koff) * C);
    const char* vb8 = (const char*)(vt + ((size_t)b * 64 + (koff >> 6)) * (size_t)(128 * 64));

    unsigned short* PW = smP + wv * (32 * PST);  // wave-private 32 x PST P tile

    // Q fragments (B operand): qf[nt][ks], row = qrow0 + nt*16 + lo
    bf16x8 qf[2][4];
    #pragma unroll
    for (int nt = 0; nt < 2; ++nt)
        #pragma unroll
        for (int ks = 0; ks < 4; ++ks)
            qf[nt][ks] = *reinterpret_cast<const bf16x8*>(
                &q[(qrow0 + nt * 16 + lo) * C + ks * 32 + quad * 8]);

    // DMA source offsets (bytes, kt-invariant), pre-swizzled so that linear
    // LDS granule G holds swizzled global granule; reads apply the same XOR.
    int offK[4], offV[4];
    #pragma unroll
    for (int c = 0; c < 4; ++c) {
        int G  = (wv * 4 + c) * 64 + lane;
        int kr = G >> 4;                              // K: 64 rows x 16 granules
        offK[c] = kr * 256 + (((G & 15) ^ (kr & 7)) << 4);
        int vr = G >> 3;                              // V: 128 rows x 8 granules
        offV[c] = vr * 128 + (((G & 7) ^ (vr & 7)) << 4);
    }

    auto stage = [&](int kt, unsigned short* dstKV) {
        const char* kt8 = kb8 + kt * 16384;
        const char* vt8 = vb8 + kt * 16384;
        #pragma unroll
        for (int c = 0; c < 4; ++c)
            dma16(kt8 + offK[c], dstKV + (wv * 4 + c) * 512);
        #pragma unroll
        for (int c = 0; c < 4; ++c)
            dma16(vt8 + offV[c], dstKV + 8192 + (wv * 4 + c) * 512);
    };

    float l_i[2] = { 0.f, 0.f };
    f32x4 ot[2][8] = {};   // O^T: col = qrow nt*16+lo, regs = chan ct*16+quad*4+r

    auto body = [&](const unsigned short* base) {
        const unsigned short* kc = base;
        const unsigned short* vc = base + 8192;

        // ---- S^T = K.Q^T : st[mt][nt], key = mt*16+quad*4+r, qrow = nt*16+lo
        f32x4 st[4][2] = {};
        __builtin_amdgcn_s_setprio(1);
        #pragma unroll
        for (int ks = 0; ks < 4; ++ks)
            #pragma unroll
            for (int mt = 0; mt < 4; ++mt) {
                const bf16x8 kf = *reinterpret_cast<const bf16x8*>(
                    &kc[(mt * 16 + lo) * 128 + (((ks * 4 + quad) ^ (lo & 7)) << 3)]);
                #pragma unroll
                for (int nt = 0; nt < 2; ++nt)
                    st[mt][nt] = __builtin_amdgcn_mfma_f32_16x16x32_bf16(
                        kf, qf[nt][ks], st[mt][nt], 0, 0, 0);
            }
        __builtin_amdgcn_s_setprio(0);

        // ---- per 32-key half: softmax numerator (fixed m=0) + PV ----
        #pragma unroll
        for (int h = 0; h < 2; ++h) {
            #pragma unroll
            for (int nt = 0; nt < 2; ++nt) {
                const int prow = nt * 16 + lo;
                float ps = 0.f;
                #pragma unroll
                for (int m = 0; m < 2; ++m) {
                    f32x4 s = st[2 * h + m][nt];
                    float p0 = fexp2(s[0]);
                    float p1 = fexp2(s[1]);
                    float p2 = fexp2(s[2]);
                    float p3 = fexp2(s[3]);
                    ps += (p0 + p1) + (p2 + p3);
                    u32x2 w;
                    w[0] = cvtpk(p0, p1);
                    w[1] = cvtpk(p2, p3);
                    // keys m*16+quad*4..+3 at shorts (2m+(quad>>1))*8+(quad&1)*4
                    *reinterpret_cast<u32x2*>(
                        &PW[prow * PST + (2 * m + (quad >> 1)) * 8
                            + (quad & 1) * 4]) = w;
                }
                l_i[nt] += ps;
            }
            bf16x8 pf[2];
            #pragma unroll
            for (int nt = 0; nt < 2; ++nt) {
                const int prow = nt * 16 + lo;
                pf[nt] = *reinterpret_cast<const bf16x8*>(
                    &PW[prow * PST + quad * 8]);   // keys quad*8..+7
            }
            __builtin_amdgcn_s_setprio(1);
            #pragma unroll
            for (int ct = 0; ct < 8; ++ct) {
                const bf16x8 vf = *reinterpret_cast<const bf16x8*>(
                    &vc[(ct * 16 + lo) * 64 + (((h * 4 + quad) ^ (lo & 7)) << 3)]);
                #pragma unroll
                for (int nt = 0; nt < 2; ++nt)
                    ot[nt][ct] = __builtin_amdgcn_mfma_f32_16x16x32_bf16(
                        vf, pf[nt], ot[nt][ct], 0, 0, 0);
            }
            __builtin_amdgcn_s_setprio(0);
        }
    };

    // ---- pipeline: stage next tile (async DMA) || compute current ----
    stage(0, smA);
    __syncthreads();                         // barrier drains DMA (vmcnt 0)
    for (int kt = 0; kt < NIT; kt += 2) {
        stage(kt + 1, smB);                  // kt+1 <= NIT-1 (NIT even)
        body(smA);
        __syncthreads();
        if (kt + 2 < NIT) stage(kt + 2, smA);
        body(smB);
        __syncthreads();
    }

    // ---- row-sum reduce ----
    #pragma unroll
    for (int nt = 0; nt < 2; ++nt) {
        l_i[nt] += __shfl_xor(l_i[nt], 16);
        l_i[nt] += __shfl_xor(l_i[nt], 32);
    }
    if (quad == 0) {
        #pragma unroll
        for (int nt = 0; nt < 2; ++nt)
            lpart[(size_t)sl * TOTROWS + qrow0 + nt * 16 + lo] = l_i[nt];
    }

    // ---- coalesced epilogue: bounce O through freed LDS, full-line stores
    constexpr int OSTR = 136;                // 272 B rows (16B-aligned)
    unsigned short* obl = smA;               // 128 x 136 shorts = 34816 B
    #pragma unroll
    for (int nt = 0; nt < 2; ++nt) {
        const int row = wv * 32 + nt * 16 + lo;
        #pragma unroll
        for (int ct = 0; ct < 8; ++ct) {
            u32x2 w;
            w[0] = cvtpk(ot[nt][ct][0], ot[nt][ct][1]);
            w[1] = cvtpk(ot[nt][ct][2], ot[nt][ct][3]);
            *reinterpret_cast<u32x2*>(&obl[row * OSTR + ct * 16 + quad * 4]) = w;
        }
    }
    __syncthreads();
    {
        unsigned short* obg = opart + (size_t)sl * TOTROWS * C;
        const int row  = tid >> 1;
        const int half = tid & 1;
        const unsigned short* src = &obl[row * OSTR + half * 64];
        unsigned short*       dst = &obg[((size_t)rowb + row) * C + half * 64];
        #pragma unroll
        for (int i = 0; i < 8; ++i)
            *reinterpret_cast<uint4*>(&dst[i * 8]) =
                *reinterpret_cast<const uint4*>(&src[i * 8]);
    }
}

// ---------------------------------------------------------------------------
// Combine nspl splits + residual: out = x + (sum_j O_j) / (sum_j l_j)
// ---------------------------------------------------------------------------
__global__ __launch_bounds__(256)
void combine_kernel(const float* __restrict__ x,
                    const unsigned short* __restrict__ opart,
                    const float* __restrict__ lpart,
                    float* __restrict__ out, int nspl)
{
    int gid = blockIdx.x * 256 + threadIdx.x;     // TOTROWS*32
    int row = gid >> 5;
    int c4  = (gid & 31) * 4;

    float denom = 0.f;
    for (int j = 0; j < nspl; ++j) denom += lpart[(size_t)j * TOTROWS + row];
    float inv = 1.0f / denom;

    size_t idx = (size_t)row * C + c4;
    float a0 = 0.f, a1 = 0.f, a2 = 0.f, a3 = 0.f;
    for (int j = 0; j < nspl; ++j) {
        u32x2 o = *reinterpret_cast<const u32x2*>(
            &opart[(size_t)j * TOTROWS * C + idx]);
        a0 += bf2f(o[0] & 0xffff);
        a1 += bf2f(o[0] >> 16);
        a2 += bf2f(o[1] & 0xffff);
        a3 += bf2f(o[1] >> 16);
    }
    float4 xv = *reinterpret_cast<const float4*>(&x[idx]);
    float4 o;
    o.x = xv.x + a0 * inv;
    o.y = xv.y + a1 * inv;
    o.z = xv.z + a2 * inv;
    o.w = xv.w + a3 * inv;
    *reinterpret_cast<float4*>(&out[idx]) = o;
}

// ---------------------------------------------------------------------------
extern "C" void kernel_launch(void* const* d_in, const int* in_sizes, int n_in,
                              void* d_out, int out_size, void* d_ws, size_t ws_size,
                              hipStream_t stream)
{
    const float* x  = (const float*)d_in[0];
    const float* Wq = (const float*)d_in[1];
    const float* bq = (const float*)d_in[2];
    const float* Wk = (const float*)d_in[3];
    const float* bk = (const float*)d_in[4];
    const float* Wv = (const float*)d_in[5];
    const float* bv = (const float*)d_in[6];
    float* out = (float*)d_out;

    // nspl=4 needs ~29 MB of ws; fall back to 2 if the workspace is small.
    const int nspl = (ws_size >= ((size_t)31 << 20)) ? 4 : 2;

    const size_t SPLIT_BYTES = (size_t)TOTROWS * C * 2;   // 4 MB
    char* ws = (char*)d_ws;
    unsigned short* opart = (unsigned short*)ws;                  // nspl*4 MB
    char* base = ws + (size_t)nspl * SPLIT_BYTES;
    unsigned short* q  = (unsigned short*)(base);                    // 4 MB
    unsigned short* k  = (unsigned short*)(base + SPLIT_BYTES);      // 4 MB
    unsigned short* vt = (unsigned short*)(base + 2 * SPLIT_BYTES);  // 4 MB (tiled)
    float*          lp = (float*)(base + 3 * SPLIT_BYTES);           // nspl*64 KB
    unsigned short* wt = (unsigned short*)(base + 3 * SPLIT_BYTES
                                           + (size_t)nspl * TOTROWS * 4); // 96 KB

    wprep_kernel<<<3, 256, 0, stream>>>(Wq, Wk, Wv, wt);
    qkv_kernel<<<dim3(TOTROWS / 64, 3), 256, 0, stream>>>(
        x, wt, bq, bk, bv, q, k, vt);
    attn_kernel<<<nspl * 128, 256, 0, stream>>>(q, k, vt, opart, lp);
    combine_kernel<<<TOTROWS * 32 / 256, 256, 0, stream>>>(x, opart, lp, out, nspl);
}

// Round 11
// 138.637 us; speedup vs baseline: 1.0209x; 1.0209x over previous
//
#include <hip/hip_runtime.h>

// Problem constants: x [4, 64, 64, 128] fp32
constexpr int C       = 128;
constexpr int N       = 4096;
constexpr int BATCH   = 4;
constexpr int TOTROWS = BATCH * N;            // 16384
constexpr float SCALE = 0.08838834764831845f; // 1/sqrt(128)
constexpr float LOG2E = 1.44269504088896340736f;

constexpr int BK  = 64;    // keys per iteration
constexpr int PST = 36;    // P-tile row stride in shorts (72B: bank-minimal)

typedef __attribute__((ext_vector_type(8))) short        bf16x8;
typedef __attribute__((ext_vector_type(4))) float        f32x4;
typedef __attribute__((ext_vector_type(2))) unsigned int u32x2;

__device__ inline unsigned short f2bf(float f) {   // RNE float->bf16 (scalar)
    unsigned int u = __float_as_uint(f);
    return (unsigned short)((u + 0x7FFFu + ((u >> 16) & 1u)) >> 16);
}
// packed RNE f32x2 -> bf16x2 in ONE instruction
__device__ inline unsigned int cvtpk(float a, float b) {
    unsigned int r;
    asm("v_cvt_pk_bf16_f32 %0, %1, %2" : "=v"(r) : "v"(a), "v"(b));
    return r;
}
__device__ inline float bf2f(unsigned int u) {
    return __uint_as_float(u << 16);
}
// bare v_exp_f32 (q is pre-scaled by LOG2E; no OCML range-fixup needed)
__device__ inline float fexp2(float x) {
#if __has_builtin(__builtin_amdgcn_exp2f)
    return __builtin_amdgcn_exp2f(x);
#else
    float r; asm("v_exp_f32 %0, %1\n\ts_nop 0" : "=v"(r) : "v"(x)); return r;
#endif
}
// async global->LDS DMA, 16B per lane; LDS dest = wave-uniform base + lane*16
__device__ inline void dma16(const void* g, void* l) {
    __builtin_amdgcn_global_load_lds(
        (const __attribute__((address_space(1))) void*)g,
        (__attribute__((address_space(3))) void*)l, 16, 0, 0);
}

// ---------------------------------------------------------------------------
// wprep (r8-verified): one-time W transpose (3 blocks x 256 thr), contiguous
// 16B stores. granule g of row o holds W[i][o], i = ((g&8)|((g&7)^xr))*8+e,
// xr=(o>>2)&7 — the exact swizzled LDS image qkv's MFMA reads expect.
// ---------------------------------------------------------------------------
__global__ __launch_bounds__(256)
void wprep_kernel(const float* __restrict__ Wq, const float* __restrict__ Wk,
                  const float* __restrict__ Wv, unsigned short* __restrict__ wt)
{
    const int mat = blockIdx.x;
    const float* W = (mat == 0) ? Wq : (mat == 1) ? Wk : Wv;
    const float  s = (mat == 0) ? SCALE * LOG2E : 1.0f;
    unsigned short* dst = wt + mat * 16384;

    const int t  = threadIdx.x;
    const int o  = t >> 1;             // output chan (W^T row), 0..127
    const int g0 = (t & 1) * 8;        // granule half
    const int xr = (o >> 2) & 7;
    #pragma unroll
    for (int gg = 0; gg < 8; ++gg) {
        const int g   = g0 + gg;
        const int ihi = (g & 8) | ((g & 7) ^ xr);
        const int i0  = ihi << 3;
        union { unsigned short u16[8]; uint4 v; } buf;
        #pragma unroll
        for (int e = 0; e < 8; ++e)
            buf.u16[e] = f2bf(W[(i0 + e) * 128 + o] * s);
        *reinterpret_cast<uint4*>(&dst[o * 128 + g * 8]) = buf.v;
    }
}

// ---------------------------------------------------------------------------
// qkv (r9-verified): grid (TOTROWS/64, 3) = 768 blocks; W-image DMA issued
// before the x loads; single barrier; verified epilogues.
// ---------------------------------------------------------------------------
__global__ __launch_bounds__(256, 2)
void qkv_kernel(const float* __restrict__ x, const unsigned short* __restrict__ wt,
                const float* __restrict__ bq, const float* __restrict__ bk,
                const float* __restrict__ bv,
                unsigned short* __restrict__ qo,
                unsigned short* __restrict__ ko,
                unsigned short* __restrict__ vt)
{
    __shared__ __align__(16) unsigned short wl[16384];   // 32768 B

    const int tid  = threadIdx.x;
    const int lane = tid & 63;
    const int lo   = lane & 15;
    const int quad = lane >> 4;
    const int mat  = blockIdx.y;
    const long rowbase = (long)blockIdx.x * 64 + (tid >> 6) * 16;

    // issue W-image DMA first: latency hides under the x loads below
    {
        const char* src = (const char*)(wt + mat * 16384);
        #pragma unroll
        for (int c = 0; c < 8; ++c)
            dma16(src + (c * 256 + tid) * 16, &wl[(c * 256 + tid) * 8]);
    }

    // x fragments (row = rowbase+lo, k = ks*32+quad*8), fp32->bf16 in regs.
    bf16x8 xf[4];
    {
        const float4* xr = reinterpret_cast<const float4*>(&x[(rowbase + lo) * C]);
        #pragma unroll
        for (int ks = 0; ks < 4; ++ks) {
            float4 a  = xr[ks * 8 + quad * 2];
            float4 b2 = xr[ks * 8 + quad * 2 + 1];
            union { bf16x8 v; unsigned int u[4]; } cv;
            cv.u[0] = cvtpk(a.x, a.y);
            cv.u[1] = cvtpk(a.z, a.w);
            cv.u[2] = cvtpk(b2.x, b2.y);
            cv.u[3] = cvtpk(b2.z, b2.w);
            xf[ks] = cv.v;
        }
    }

    __syncthreads();                  // drains DMA (vmcnt 0)

    if (mat < 2) {
        // q/k: D[m=outchan][n=row], A=W^T frag, B=xf -> row-major store
        f32x4 acc[8] = {};
        #pragma unroll
        for (int ks = 0; ks < 4; ++ks)
            #pragma unroll
            for (int mt = 0; mt < 8; ++mt) {
                const int rr = mt * 16 + lo;
                bf16x8 wf = *reinterpret_cast<const bf16x8*>(
                    &wl[rr * 128 + (((ks * 4 + quad) ^ ((rr >> 2) & 7)) << 3)]);
                acc[mt] = __builtin_amdgcn_mfma_f32_16x16x32_bf16(
                    wf, xf[ks], acc[mt], 0, 0, 0);
            }
        const float* bias = (mat == 0) ? bq : bk;
        const float  s    = (mat == 0) ? SCALE * LOG2E : 1.0f;
        unsigned short* out = (mat == 0) ? qo : ko;
        long row = rowbase + lo;
        #pragma unroll
        for (int mt = 0; mt < 8; ++mt) {
            float4 bb = *reinterpret_cast<const float4*>(&bias[mt * 16 + quad * 4]);
            u32x2 w;
            w[0] = cvtpk(acc[mt][0] + bb.x * s, acc[mt][1] + bb.y * s);
            w[1] = cvtpk(acc[mt][2] + bb.z * s, acc[mt][3] + bb.w * s);
            *reinterpret_cast<u32x2*>(&out[row * C + mt * 16 + quad * 4]) = w;
        }
    } else {
        // v: D[m=row][n=chan], A=xf, B=W^T frag -> tiled transposed store
        f32x4 acc[8] = {};
        #pragma unroll
        for (int ks = 0; ks < 4; ++ks)
            #pragma unroll
            for (int ct = 0; ct < 8; ++ct) {
                const int rr = ct * 16 + lo;
                bf16x8 wf = *reinterpret_cast<const bf16x8*>(
                    &wl[rr * 128 + (((ks * 4 + quad) ^ ((rr >> 2) & 7)) << 3)]);
                acc[ct] = __builtin_amdgcn_mfma_f32_16x16x32_bf16(
                    xf[ks], wf, acc[ct], 0, 0, 0);
            }
        const int b = (int)(rowbase >> 12);
        const int nbase = (int)(rowbase & (N - 1));
        const int n0   = nbase + quad * 4;
        const int nblk = n0 >> 6;
        #pragma unroll
        for (int ct = 0; ct < 8; ++ct) {
            int chan = ct * 16 + lo;
            float bb = bv[chan];
            u32x2 w;
            w[0] = cvtpk(acc[ct][0] + bb, acc[ct][1] + bb);
            w[1] = cvtpk(acc[ct][2] + bb, acc[ct][3] + bb);
            *reinterpret_cast<u32x2*>(
                &vt[(((size_t)b * 64 + nblk) * 128 + chan) * 64 + (n0 & 63)]) = w;
        }
    }
}

// ---------------------------------------------------------------------------
// Flash attention, round-24: r10 MINUS setprio (single-variable isolation).
// r10 post-mortem: P-tile pad fix verified by counters (conflicts 5.9M->2.2M)
// but time regressed 48.8->55.7us with setprio bundled in. Guide m190:
// setprio HURTS barrier-lockstep structures — our 4 waves/block are
// lockstepped on 2 barriers/iter, and only 2 blocks/CU share the SIMD; a
// priority-boosted MFMA wave starves the other block's staging. Removed.
// P layout keeps stride PST=36 shorts (72B): prow*18 mod 32 covers all 16
// even banks; b64 writes and b128 reads at theoretical minimum.
// LDS: 34944 + 32768 + 9216 = 76,928 B -> 2 blocks/CU.
// ---------------------------------------------------------------------------
__global__ __launch_bounds__(256, 2)
void attn_kernel(const unsigned short* __restrict__ q,
                 const unsigned short* __restrict__ k,
                 const unsigned short* __restrict__ vt,
                 unsigned short* __restrict__ opart,
                 float* __restrict__ lpart)
{
    // buffer A: K0 @0 (8192), V0 @8192 (8192), pad to 17472 shorts;
    //           reused as O-bounce (128 x 136 shorts) in the epilogue
    __shared__ __align__(16) unsigned short smA[17472];  // 34944 B
    __shared__ __align__(16) unsigned short smB[16384];  // 32768 B (K1,V1)
    __shared__ __align__(16) unsigned short smP[4608];   //  9216 B (4 x 32 x PST)

    const int tid  = threadIdx.x;
    const int wv   = tid >> 6;          // 0..3
    const int lane = tid & 63;
    const int lo   = lane & 15;
    const int quad = lane >> 4;

    const int nspl = (int)(gridDim.x >> 7);      // 512 -> 4, 256 -> 2
    const int id   = blockIdx.x;
    int b, sl, qt;
    if (nspl == 4) {         // id%8 = b*2 + (sl&1): pins (batch,parity) to XCD
        b  = (id >> 1) & 3;
        sl = (id & 1) | (((id >> 3) & 1) << 1);
        qt = id >> 4;        // 0..31
    } else {
        b  = (id >> 1) & 3;
        sl = id & 1;
        qt = id >> 3;
    }
    const int NIT  = (N / nspl) / BK;            // 16 (nspl=4), even
    const int koff = sl * (N / nspl);

    const int    rowb  = b * N + qt * 128;       // block's first q-row (global)
    const size_t qrow0 = (size_t)rowb + wv * 32; // wave's first q-row
    const char* kb8 = (const char*)(k  + ((size_t)b * N + koff) * C);
    const char* vb8 = (const char*)(vt + ((size_t)b * 64 + (koff >> 6)) * (size_t)(128 * 64));

    unsigned short* PW = smP + wv * (32 * PST);  // wave-private 32 x PST P tile

    // Q fragments (B operand): qf[nt][ks], row = qrow0 + nt*16 + lo
    bf16x8 qf[2][4];
    #pragma unroll
    for (int nt = 0; nt < 2; ++nt)
        #pragma unroll
        for (int ks = 0; ks < 4; ++ks)
            qf[nt][ks] = *reinterpret_cast<const bf16x8*>(
                &q[(qrow0 + nt * 16 + lo) * C + ks * 32 + quad * 8]);

    // DMA source offsets (bytes, kt-invariant), pre-swizzled so that linear
    // LDS granule G holds swizzled global granule; reads apply the same XOR.
    int offK[4], offV[4];
    #pragma unroll
    for (int c = 0; c < 4; ++c) {
        int G  = (wv * 4 + c) * 64 + lane;
        int kr = G >> 4;                              // K: 64 rows x 16 granules
        offK[c] = kr * 256 + (((G & 15) ^ (kr & 7)) << 4);
        int vr = G >> 3;                              // V: 128 rows x 8 granules
        offV[c] = vr * 128 + (((G & 7) ^ (vr & 7)) << 4);
    }

    auto stage = [&](int kt, unsigned short* dstKV) {
        const char* kt8 = kb8 + kt * 16384;
        const char* vt8 = vb8 + kt * 16384;
        #pragma unroll
        for (int c = 0; c < 4; ++c)
            dma16(kt8 + offK[c], dstKV + (wv * 4 + c) * 512);
        #pragma unroll
        for (int c = 0; c < 4; ++c)
            dma16(vt8 + offV[c], dstKV + 8192 + (wv * 4 + c) * 512);
    };

    float l_i[2] = { 0.f, 0.f };
    f32x4 ot[2][8] = {};   // O^T: col = qrow nt*16+lo, regs = chan ct*16+quad*4+r

    auto body = [&](const unsigned short* base) {
        const unsigned short* kc = base;
        const unsigned short* vc = base + 8192;

        // ---- S^T = K.Q^T : st[mt][nt], key = mt*16+quad*4+r, qrow = nt*16+lo
        f32x4 st[4][2] = {};
        #pragma unroll
        for (int ks = 0; ks < 4; ++ks)
            #pragma unroll
            for (int mt = 0; mt < 4; ++mt) {
                const bf16x8 kf = *reinterpret_cast<const bf16x8*>(
                    &kc[(mt * 16 + lo) * 128 + (((ks * 4 + quad) ^ (lo & 7)) << 3)]);
                #pragma unroll
                for (int nt = 0; nt < 2; ++nt)
                    st[mt][nt] = __builtin_amdgcn_mfma_f32_16x16x32_bf16(
                        kf, qf[nt][ks], st[mt][nt], 0, 0, 0);
            }

        // ---- per 32-key half: softmax numerator (fixed m=0) + PV ----
        #pragma unroll
        for (int h = 0; h < 2; ++h) {
            #pragma unroll
            for (int nt = 0; nt < 2; ++nt) {
                const int prow = nt * 16 + lo;
                float ps = 0.f;
                #pragma unroll
                for (int m = 0; m < 2; ++m) {
                    f32x4 s = st[2 * h + m][nt];
                    float p0 = fexp2(s[0]);
                    float p1 = fexp2(s[1]);
                    float p2 = fexp2(s[2]);
                    float p3 = fexp2(s[3]);
                    ps += (p0 + p1) + (p2 + p3);
                    u32x2 w;
                    w[0] = cvtpk(p0, p1);
                    w[1] = cvtpk(p2, p3);
                    // keys m*16+quad*4..+3 at shorts (2m+(quad>>1))*8+(quad&1)*4
                    *reinterpret_cast<u32x2*>(
                        &PW[prow * PST + (2 * m + (quad >> 1)) * 8
                            + (quad & 1) * 4]) = w;
                }
                l_i[nt] += ps;
            }
            bf16x8 pf[2];
            #pragma unroll
            for (int nt = 0; nt < 2; ++nt) {
                const int prow = nt * 16 + lo;
                pf[nt] = *reinterpret_cast<const bf16x8*>(
                    &PW[prow * PST + quad * 8]);   // keys quad*8..+7
            }
            #pragma unroll
            for (int ct = 0; ct < 8; ++ct) {
                const bf16x8 vf = *reinterpret_cast<const bf16x8*>(
                    &vc[(ct * 16 + lo) * 64 + (((h * 4 + quad) ^ (lo & 7)) << 3)]);
                #pragma unroll
                for (int nt = 0; nt < 2; ++nt)
                    ot[nt][ct] = __builtin_amdgcn_mfma_f32_16x16x32_bf16(
                        vf, pf[nt], ot[nt][ct], 0, 0, 0);
            }
        }
    };

    // ---- pipeline: stage next tile (async DMA) || compute current ----
    stage(0, smA);
    __syncthreads();                         // barrier drains DMA (vmcnt 0)
    for (int kt = 0; kt < NIT; kt += 2) {
        stage(kt + 1, smB);                  // kt+1 <= NIT-1 (NIT even)
        body(smA);
        __syncthreads();
        if (kt + 2 < NIT) stage(kt + 2, smA);
        body(smB);
        __syncthreads();
    }

    // ---- row-sum reduce ----
    #pragma unroll
    for (int nt = 0; nt < 2; ++nt) {
        l_i[nt] += __shfl_xor(l_i[nt], 16);
        l_i[nt] += __shfl_xor(l_i[nt], 32);
    }
    if (quad == 0) {
        #pragma unroll
        for (int nt = 0; nt < 2; ++nt)
            lpart[(size_t)sl * TOTROWS + qrow0 + nt * 16 + lo] = l_i[nt];
    }

    // ---- coalesced epilogue: bounce O through freed LDS, full-line stores
    constexpr int OSTR = 136;                // 272 B rows (16B-aligned)
    unsigned short* obl = smA;               // 128 x 136 shorts = 34816 B
    #pragma unroll
    for (int nt = 0; nt < 2; ++nt) {
        const int row = wv * 32 + nt * 16 + lo;
        #pragma unroll
        for (int ct = 0; ct < 8; ++ct) {
            u32x2 w;
            w[0] = cvtpk(ot[nt][ct][0], ot[nt][ct][1]);
            w[1] = cvtpk(ot[nt][ct][2], ot[nt][ct][3]);
            *reinterpret_cast<u32x2*>(&obl[row * OSTR + ct * 16 + quad * 4]) = w;
        }
    }
    __syncthreads();
    {
        unsigned short* obg = opart + (size_t)sl * TOTROWS * C;
        const int row  = tid >> 1;
        const int half = tid & 1;
        const unsigned short* src = &obl[row * OSTR + half * 64];
        unsigned short*       dst = &obg[((size_t)rowb + row) * C + half * 64];
        #pragma unroll
        for (int i = 0; i < 8; ++i)
            *reinterpret_cast<uint4*>(&dst[i * 8]) =
                *reinterpret_cast<const uint4*>(&src[i * 8]);
    }
}

// ---------------------------------------------------------------------------
// Combine nspl splits + residual: out = x + (sum_j O_j) / (sum_j l_j)
// ---------------------------------------------------------------------------
__global__ __launch_bounds__(256)
void combine_kernel(const float* __restrict__ x,
                    const unsigned short* __restrict__ opart,
                    const float* __restrict__ lpart,
                    float* __restrict__ out, int nspl)
{
    int gid = blockIdx.x * 256 + threadIdx.x;     // TOTROWS*32
    int row = gid >> 5;
    int c4  = (gid & 31) * 4;

    float denom = 0.f;
    for (int j = 0; j < nspl; ++j) denom += lpart[(size_t)j * TOTROWS + row];
    float inv = 1.0f / denom;

    size_t idx = (size_t)row * C + c4;
    float a0 = 0.f, a1 = 0.f, a2 = 0.f, a3 = 0.f;
    for (int j = 0; j < nspl; ++j) {
        u32x2 o = *reinterpret_cast<const u32x2*>(
            &opart[(size_t)j * TOTROWS * C + idx]);
        a0 += bf2f(o[0] & 0xffff);
        a1 += bf2f(o[0] >> 16);
        a2 += bf2f(o[1] & 0xffff);
        a3 += bf2f(o[1] >> 16);
    }
    float4 xv = *reinterpret_cast<const float4*>(&x[idx]);
    float4 o;
    o.x = xv.x + a0 * inv;
    o.y = xv.y + a1 * inv;
    o.z = xv.z + a2 * inv;
    o.w = xv.w + a3 * inv;
    *reinterpret_cast<float4*>(&out[idx]) = o;
}

// ---------------------------------------------------------------------------
extern "C" void kernel_launch(void* const* d_in, const int* in_sizes, int n_in,
                              void* d_out, int out_size, void* d_ws, size_t ws_size,
                              hipStream_t stream)
{
    const float* x  = (const float*)d_in[0];
    const float* Wq = (const float*)d_in[1];
    const float* bq = (const float*)d_in[2];
    const float* Wk = (const float*)d_in[3];
    const float* bk = (const float*)d_in[4];
    const float* Wv = (const float*)d_in[5];
    const float* bv = (const float*)d_in[6];
    float* out = (float*)d_out;

    // nspl=4 needs ~29 MB of ws; fall back to 2 if the workspace is small.
    const int nspl = (ws_size >= ((size_t)31 << 20)) ? 4 : 2;

    const size_t SPLIT_BYTES = (size_t)TOTROWS * C * 2;   // 4 MB
    char* ws = (char*)d_ws;
    unsigned short* opart = (unsigned short*)ws;                  // nspl*4 MB
    char* base = ws + (size_t)nspl * SPLIT_BYTES;
    unsigned short* q  = (unsigned short*)(base);                    // 4 MB
    unsigned short* k  = (unsigned short*)(base + SPLIT_BYTES);      // 4 MB
    unsigned short* vt = (unsigned short*)(base + 2 * SPLIT_BYTES);  // 4 MB (tiled)
    float*          lp = (float*)(base + 3 * SPLIT_BYTES);           // nspl*64 KB
    unsigned short* wt = (unsigned short*)(base + 3 * SPLIT_BYTES
                                           + (size_t)nspl * TOTROWS * 4); // 96 KB

    wprep_kernel<<<3, 256, 0, stream>>>(Wq, Wk, Wv, wt);
    qkv_kernel<<<dim3(TOTROWS / 64, 3), 256, 0, stream>>>(
        x, wt, bq, bk, bv, q, k, vt);
    attn_kernel<<<nspl * 128, 256, 0, stream>>>(q, k, vt, opart, lp);
    combine_kernel<<<TOTROWS * 32 / 256, 256, 0, stream>>>(x, opart, lp, out, nspl);
}

// Round 12
// 128.294 us; speedup vs baseline: 1.1032x; 1.0806x over previous
//
#include <hip/hip_runtime.h>

// Problem constants: x [4, 64, 64, 128] fp32
constexpr int C       = 128;
constexpr int N       = 4096;
constexpr int BATCH   = 4;
constexpr int TOTROWS = BATCH * N;            // 16384
constexpr float SCALE = 0.08838834764831845f; // 1/sqrt(128)
constexpr float LOG2E = 1.44269504088896340736f;

constexpr int BK = 64;     // keys per iteration

typedef __attribute__((ext_vector_type(8))) short        bf16x8;
typedef __attribute__((ext_vector_type(4))) float        f32x4;
typedef __attribute__((ext_vector_type(2))) unsigned int u32x2;

__device__ inline unsigned short f2bf(float f) {   // RNE float->bf16 (scalar)
    unsigned int u = __float_as_uint(f);
    return (unsigned short)((u + 0x7FFFu + ((u >> 16) & 1u)) >> 16);
}
// packed RNE f32x2 -> bf16x2 in ONE instruction
__device__ inline unsigned int cvtpk(float a, float b) {
    unsigned int r;
    asm("v_cvt_pk_bf16_f32 %0, %1, %2" : "=v"(r) : "v"(a), "v"(b));
    return r;
}
__device__ inline float bf2f(unsigned int u) {
    return __uint_as_float(u << 16);
}
// bare v_exp_f32 (q is pre-scaled by LOG2E; no OCML range-fixup needed)
__device__ inline float fexp2(float x) {
#if __has_builtin(__builtin_amdgcn_exp2f)
    return __builtin_amdgcn_exp2f(x);
#else
    float r; asm("v_exp_f32 %0, %1\n\ts_nop 0" : "=v"(r) : "v"(x)); return r;
#endif
}
// async global->LDS DMA, 16B per lane; LDS dest = wave-uniform base + lane*16
__device__ inline void dma16(const void* g, void* l) {
    __builtin_amdgcn_global_load_lds(
        (const __attribute__((address_space(1))) void*)g,
        (__attribute__((address_space(3))) void*)l, 16, 0, 0);
}

// ---------------------------------------------------------------------------
// wprep (r8-verified): one-time W transpose (3 blocks x 256 thr), contiguous
// 16B stores. granule g of row o holds W[i][o], i = ((g&8)|((g&7)^xr))*8+e,
// xr=(o>>2)&7 — the exact swizzled LDS image qkv's MFMA reads expect.
// ---------------------------------------------------------------------------
__global__ __launch_bounds__(256)
void wprep_kernel(const float* __restrict__ Wq, const float* __restrict__ Wk,
                  const float* __restrict__ Wv, unsigned short* __restrict__ wt)
{
    const int mat = blockIdx.x;
    const float* W = (mat == 0) ? Wq : (mat == 1) ? Wk : Wv;
    const float  s = (mat == 0) ? SCALE * LOG2E : 1.0f;
    unsigned short* dst = wt + mat * 16384;

    const int t  = threadIdx.x;
    const int o  = t >> 1;             // output chan (W^T row), 0..127
    const int g0 = (t & 1) * 8;        // granule half
    const int xr = (o >> 2) & 7;
    #pragma unroll
    for (int gg = 0; gg < 8; ++gg) {
        const int g   = g0 + gg;
        const int ihi = (g & 8) | ((g & 7) ^ xr);
        const int i0  = ihi << 3;
        union { unsigned short u16[8]; uint4 v; } buf;
        #pragma unroll
        for (int e = 0; e < 8; ++e)
            buf.u16[e] = f2bf(W[(i0 + e) * 128 + o] * s);
        *reinterpret_cast<uint4*>(&dst[o * 128 + g * 8]) = buf.v;
    }
}

// ---------------------------------------------------------------------------
// qkv (r9-verified): grid (TOTROWS/64, 3) = 768 blocks; W-image DMA issued
// before the x loads; single barrier; verified epilogues.
// ---------------------------------------------------------------------------
__global__ __launch_bounds__(256, 2)
void qkv_kernel(const float* __restrict__ x, const unsigned short* __restrict__ wt,
                const float* __restrict__ bq, const float* __restrict__ bk,
                const float* __restrict__ bv,
                unsigned short* __restrict__ qo,
                unsigned short* __restrict__ ko,
                unsigned short* __restrict__ vt)
{
    __shared__ __align__(16) unsigned short wl[16384];   // 32768 B

    const int tid  = threadIdx.x;
    const int lane = tid & 63;
    const int lo   = lane & 15;
    const int quad = lane >> 4;
    const int mat  = blockIdx.y;
    const long rowbase = (long)blockIdx.x * 64 + (tid >> 6) * 16;

    // issue W-image DMA first: latency hides under the x loads below
    {
        const char* src = (const char*)(wt + mat * 16384);
        #pragma unroll
        for (int c = 0; c < 8; ++c)
            dma16(src + (c * 256 + tid) * 16, &wl[(c * 256 + tid) * 8]);
    }

    // x fragments (row = rowbase+lo, k = ks*32+quad*8), fp32->bf16 in regs.
    bf16x8 xf[4];
    {
        const float4* xr = reinterpret_cast<const float4*>(&x[(rowbase + lo) * C]);
        #pragma unroll
        for (int ks = 0; ks < 4; ++ks) {
            float4 a  = xr[ks * 8 + quad * 2];
            float4 b2 = xr[ks * 8 + quad * 2 + 1];
            union { bf16x8 v; unsigned int u[4]; } cv;
            cv.u[0] = cvtpk(a.x, a.y);
            cv.u[1] = cvtpk(a.z, a.w);
            cv.u[2] = cvtpk(b2.x, b2.y);
            cv.u[3] = cvtpk(b2.z, b2.w);
            xf[ks] = cv.v;
        }
    }

    __syncthreads();                  // drains DMA (vmcnt 0)

    if (mat < 2) {
        // q/k: D[m=outchan][n=row], A=W^T frag, B=xf -> row-major store
        f32x4 acc[8] = {};
        #pragma unroll
        for (int ks = 0; ks < 4; ++ks)
            #pragma unroll
            for (int mt = 0; mt < 8; ++mt) {
                const int rr = mt * 16 + lo;
                bf16x8 wf = *reinterpret_cast<const bf16x8*>(
                    &wl[rr * 128 + (((ks * 4 + quad) ^ ((rr >> 2) & 7)) << 3)]);
                acc[mt] = __builtin_amdgcn_mfma_f32_16x16x32_bf16(
                    wf, xf[ks], acc[mt], 0, 0, 0);
            }
        const float* bias = (mat == 0) ? bq : bk;
        const float  s    = (mat == 0) ? SCALE * LOG2E : 1.0f;
        unsigned short* out = (mat == 0) ? qo : ko;
        long row = rowbase + lo;
        #pragma unroll
        for (int mt = 0; mt < 8; ++mt) {
            float4 bb = *reinterpret_cast<const float4*>(&bias[mt * 16 + quad * 4]);
            u32x2 w;
            w[0] = cvtpk(acc[mt][0] + bb.x * s, acc[mt][1] + bb.y * s);
            w[1] = cvtpk(acc[mt][2] + bb.z * s, acc[mt][3] + bb.w * s);
            *reinterpret_cast<u32x2*>(&out[row * C + mt * 16 + quad * 4]) = w;
        }
    } else {
        // v: D[m=row][n=chan], A=xf, B=W^T frag -> tiled transposed store
        f32x4 acc[8] = {};
        #pragma unroll
        for (int ks = 0; ks < 4; ++ks)
            #pragma unroll
            for (int ct = 0; ct < 8; ++ct) {
                const int rr = ct * 16 + lo;
                bf16x8 wf = *reinterpret_cast<const bf16x8*>(
                    &wl[rr * 128 + (((ks * 4 + quad) ^ ((rr >> 2) & 7)) << 3)]);
                acc[ct] = __builtin_amdgcn_mfma_f32_16x16x32_bf16(
                    xf[ks], wf, acc[ct], 0, 0, 0);
            }
        const int b = (int)(rowbase >> 12);
        const int nbase = (int)(rowbase & (N - 1));
        const int n0   = nbase + quad * 4;
        const int nblk = n0 >> 6;
        #pragma unroll
        for (int ct = 0; ct < 8; ++ct) {
            int chan = ct * 16 + lo;
            float bb = bv[chan];
            u32x2 w;
            w[0] = cvtpk(acc[ct][0] + bb, acc[ct][1] + bb);
            w[1] = cvtpk(acc[ct][2] + bb, acc[ct][3] + bb);
            *reinterpret_cast<u32x2*>(
                &vt[(((size_t)b * 64 + nblk) * 128 + chan) * 64 + (n0 & 63)]) = w;
        }
    }
}

// ---------------------------------------------------------------------------
// Flash attention — REVERTED to the r9-exact body (best verified: 46.4-48.8us,
// total 132.4). Round-11 isolated both r10 levers as regressions:
//  - setprio: -2.7us (m190: hurts barrier-lockstep waves)
//  - P-pad PST=36: -4.2us despite conflicts 5.9M->2.2M (conflicts were fully
//    hidden under latency; the pad's mul-addressing cost more than it saved)
// Ledger: occupancy x2 (null x2), LDS traffic /1.7 (null), conflicts /2.7
// (negative), intra-wave interleave (raced x2), split-K fusion (catastrophic),
// setprio (negative). This structure is a latency-bound local minimum; keep
// the verified form.
// ---------------------------------------------------------------------------
__global__ __launch_bounds__(256, 2)
void attn_kernel(const unsigned short* __restrict__ q,
                 const unsigned short* __restrict__ k,
                 const unsigned short* __restrict__ vt,
                 unsigned short* __restrict__ opart,
                 float* __restrict__ lpart)
{
    // buffer A: K0 @0 (8192), V0 @8192 (8192), pad to 17472 shorts;
    //           reused as O-bounce (128 x 136 shorts) in the epilogue
    __shared__ __align__(16) unsigned short smA[17472];  // 34944 B
    __shared__ __align__(16) unsigned short smB[16384];  // 32768 B (K1,V1)
    __shared__ __align__(16) unsigned short smP[4096];   //  8192 B (4 waves x 32x32)

    const int tid  = threadIdx.x;
    const int wv   = tid >> 6;          // 0..3
    const int lane = tid & 63;
    const int lo   = lane & 15;
    const int quad = lane >> 4;

    const int nspl = (int)(gridDim.x >> 7);      // 512 -> 4, 256 -> 2
    const int id   = blockIdx.x;
    int b, sl, qt;
    if (nspl == 4) {         // id%8 = b*2 + (sl&1): pins (batch,parity) to XCD
        b  = (id >> 1) & 3;
        sl = (id & 1) | (((id >> 3) & 1) << 1);
        qt = id >> 4;        // 0..31
    } else {
        b  = (id >> 1) & 3;
        sl = id & 1;
        qt = id >> 3;
    }
    const int NIT  = (N / nspl) / BK;            // 16 (nspl=4), even
    const int koff = sl * (N / nspl);

    const int    rowb  = b * N + qt * 128;       // block's first q-row (global)
    const size_t qrow0 = (size_t)rowb + wv * 32; // wave's first q-row
    const char* kb8 = (const char*)(k  + ((size_t)b * N + koff) * C);
    const char* vb8 = (const char*)(vt + ((size_t)b * 64 + (koff >> 6)) * (size_t)(128 * 64));

    unsigned short* PW = smP + wv * 1024;        // wave-private 32x32 P tile

    // Q fragments (B operand): qf[nt][ks], row = qrow0 + nt*16 + lo
    bf16x8 qf[2][4];
    #pragma unroll
    for (int nt = 0; nt < 2; ++nt)
        #pragma unroll
        for (int ks = 0; ks < 4; ++ks)
            qf[nt][ks] = *reinterpret_cast<const bf16x8*>(
                &q[(qrow0 + nt * 16 + lo) * C + ks * 32 + quad * 8]);

    // DMA source offsets (bytes, kt-invariant), pre-swizzled so that linear
    // LDS granule G holds swizzled global granule; reads apply the same XOR.
    int offK[4], offV[4];
    #pragma unroll
    for (int c = 0; c < 4; ++c) {
        int G  = (wv * 4 + c) * 64 + lane;
        int kr = G >> 4;                              // K: 64 rows x 16 granules
        offK[c] = kr * 256 + (((G & 15) ^ (kr & 7)) << 4);
        int vr = G >> 3;                              // V: 128 rows x 8 granules
        offV[c] = vr * 128 + (((G & 7) ^ (vr & 7)) << 4);
    }

    auto stage = [&](int kt, unsigned short* dstKV) {
        const char* kt8 = kb8 + kt * 16384;
        const char* vt8 = vb8 + kt * 16384;
        #pragma unroll
        for (int c = 0; c < 4; ++c)
            dma16(kt8 + offK[c], dstKV + (wv * 4 + c) * 512);
        #pragma unroll
        for (int c = 0; c < 4; ++c)
            dma16(vt8 + offV[c], dstKV + 8192 + (wv * 4 + c) * 512);
    };

    float l_i[2] = { 0.f, 0.f };
    f32x4 ot[2][8] = {};   // O^T: col = qrow nt*16+lo, regs = chan ct*16+quad*4+r

    auto body = [&](const unsigned short* base) {
        const unsigned short* kc = base;
        const unsigned short* vc = base + 8192;

        // ---- S^T = K.Q^T : st[mt][nt], key = mt*16+quad*4+r, qrow = nt*16+lo
        f32x4 st[4][2] = {};
        #pragma unroll
        for (int ks = 0; ks < 4; ++ks)
            #pragma unroll
            for (int mt = 0; mt < 4; ++mt) {
                const bf16x8 kf = *reinterpret_cast<const bf16x8*>(
                    &kc[(mt * 16 + lo) * 128 + (((ks * 4 + quad) ^ (lo & 7)) << 3)]);
                #pragma unroll
                for (int nt = 0; nt < 2; ++nt)
                    st[mt][nt] = __builtin_amdgcn_mfma_f32_16x16x32_bf16(
                        kf, qf[nt][ks], st[mt][nt], 0, 0, 0);
            }

        // ---- per 32-key half: softmax numerator (fixed m=0) + PV ----
        #pragma unroll
        for (int h = 0; h < 2; ++h) {
            #pragma unroll
            for (int nt = 0; nt < 2; ++nt) {
                const int prow = nt * 16 + lo;
                float ps = 0.f;
                #pragma unroll
                for (int m = 0; m < 2; ++m) {
                    f32x4 s = st[2 * h + m][nt];
                    float p0 = fexp2(s[0]);
                    float p1 = fexp2(s[1]);
                    float p2 = fexp2(s[2]);
                    float p3 = fexp2(s[3]);
                    ps += (p0 + p1) + (p2 + p3);
                    u32x2 w;
                    w[0] = cvtpk(p0, p1);
                    w[1] = cvtpk(p2, p3);
                    *reinterpret_cast<u32x2*>(
                        &PW[prow * 32 + (((2 * m + (quad >> 1)) ^ (prow & 3)) << 3)
                            + (quad & 1) * 4]) = w;
                }
                l_i[nt] += ps;
            }
            bf16x8 pf[2];
            #pragma unroll
            for (int nt = 0; nt < 2; ++nt) {
                const int prow = nt * 16 + lo;
                pf[nt] = *reinterpret_cast<const bf16x8*>(
                    &PW[prow * 32 + ((quad ^ (prow & 3)) << 3)]);
            }
            #pragma unroll
            for (int ct = 0; ct < 8; ++ct) {
                const bf16x8 vf = *reinterpret_cast<const bf16x8*>(
                    &vc[(ct * 16 + lo) * 64 + (((h * 4 + quad) ^ (lo & 7)) << 3)]);
                #pragma unroll
                for (int nt = 0; nt < 2; ++nt)
                    ot[nt][ct] = __builtin_amdgcn_mfma_f32_16x16x32_bf16(
                        vf, pf[nt], ot[nt][ct], 0, 0, 0);
            }
        }
    };

    // ---- pipeline: stage next tile (async DMA) || compute current ----
    stage(0, smA);
    __syncthreads();                         // barrier drains DMA (vmcnt 0)
    for (int kt = 0; kt < NIT; kt += 2) {
        stage(kt + 1, smB);                  // kt+1 <= NIT-1 (NIT even)
        body(smA);
        __syncthreads();
        if (kt + 2 < NIT) stage(kt + 2, smA);
        body(smB);
        __syncthreads();
    }

    // ---- row-sum reduce ----
    #pragma unroll
    for (int nt = 0; nt < 2; ++nt) {
        l_i[nt] += __shfl_xor(l_i[nt], 16);
        l_i[nt] += __shfl_xor(l_i[nt], 32);
    }
    if (quad == 0) {
        #pragma unroll
        for (int nt = 0; nt < 2; ++nt)
            lpart[(size_t)sl * TOTROWS + qrow0 + nt * 16 + lo] = l_i[nt];
    }

    // ---- coalesced epilogue: bounce O through freed LDS, full-line stores
    constexpr int OSTR = 136;                // 272 B rows (16B-aligned)
    unsigned short* obl = smA;               // 128 x 136 shorts = 34816 B
    #pragma unroll
    for (int nt = 0; nt < 2; ++nt) {
        const int row = wv * 32 + nt * 16 + lo;
        #pragma unroll
        for (int ct = 0; ct < 8; ++ct) {
            u32x2 w;
            w[0] = cvtpk(ot[nt][ct][0], ot[nt][ct][1]);
            w[1] = cvtpk(ot[nt][ct][2], ot[nt][ct][3]);
            *reinterpret_cast<u32x2*>(&obl[row * OSTR + ct * 16 + quad * 4]) = w;
        }
    }
    __syncthreads();
    {
        unsigned short* obg = opart + (size_t)sl * TOTROWS * C;
        const int row  = tid >> 1;
        const int half = tid & 1;
        const unsigned short* src = &obl[row * OSTR + half * 64];
        unsigned short*       dst = &obg[((size_t)rowb + row) * C + half * 64];
        #pragma unroll
        for (int i = 0; i < 8; ++i)
            *reinterpret_cast<uint4*>(&dst[i * 8]) =
                *reinterpret_cast<const uint4*>(&src[i * 8]);
    }
}

// ---------------------------------------------------------------------------
// Combine, round-25: VECTORIZED (the one new lever this round). Each thread
// now owns 8 channels: 4x uint4 opart loads + 2x float4 x loads + 2x float4
// stores — half the threads, double the bytes/instruction (G13). Per-channel
// addition order unchanged (bit-identical output).
// ---------------------------------------------------------------------------
__global__ __launch_bounds__(256)
void combine_kernel(const float* __restrict__ x,
                    const unsigned short* __restrict__ opart,
                    const float* __restrict__ lpart,
                    float* __restrict__ out, int nspl)
{
    int gid = blockIdx.x * 256 + threadIdx.x;     // TOTROWS*16 threads
    int row = gid >> 4;
    int c8  = (gid & 15) * 8;

    float denom = 0.f;
    for (int j = 0; j < nspl; ++j) denom += lpart[(size_t)j * TOTROWS + row];
    float inv = 1.0f / denom;

    size_t idx = (size_t)row * C + c8;
    float a[8] = {};
    for (int j = 0; j < nspl; ++j) {
        uint4 o = *reinterpret_cast<const uint4*>(
            &opart[(size_t)j * TOTROWS * C + idx]);
        a[0] += bf2f(o.x & 0xffff);  a[1] += bf2f(o.x >> 16);
        a[2] += bf2f(o.y & 0xffff);  a[3] += bf2f(o.y >> 16);
        a[4] += bf2f(o.z & 0xffff);  a[5] += bf2f(o.z >> 16);
        a[6] += bf2f(o.w & 0xffff);  a[7] += bf2f(o.w >> 16);
    }
    float4 xv0 = *reinterpret_cast<const float4*>(&x[idx]);
    float4 xv1 = *reinterpret_cast<const float4*>(&x[idx + 4]);
    float4 o0, o1;
    o0.x = xv0.x + a[0] * inv;  o0.y = xv0.y + a[1] * inv;
    o0.z = xv0.z + a[2] * inv;  o0.w = xv0.w + a[3] * inv;
    o1.x = xv1.x + a[4] * inv;  o1.y = xv1.y + a[5] * inv;
    o1.z = xv1.z + a[6] * inv;  o1.w = xv1.w + a[7] * inv;
    *reinterpret_cast<float4*>(&out[idx])     = o0;
    *reinterpret_cast<float4*>(&out[idx + 4]) = o1;
}

// ---------------------------------------------------------------------------
extern "C" void kernel_launch(void* const* d_in, const int* in_sizes, int n_in,
                              void* d_out, int out_size, void* d_ws, size_t ws_size,
                              hipStream_t stream)
{
    const float* x  = (const float*)d_in[0];
    const float* Wq = (const float*)d_in[1];
    const float* bq = (const float*)d_in[2];
    const float* Wk = (const float*)d_in[3];
    const float* bk = (const float*)d_in[4];
    const float* Wv = (const float*)d_in[5];
    const float* bv = (const float*)d_in[6];
    float* out = (float*)d_out;

    // nspl=4 needs ~29 MB of ws; fall back to 2 if the workspace is small.
    const int nspl = (ws_size >= ((size_t)31 << 20)) ? 4 : 2;

    const size_t SPLIT_BYTES = (size_t)TOTROWS * C * 2;   // 4 MB
    char* ws = (char*)d_ws;
    unsigned short* opart = (unsigned short*)ws;                  // nspl*4 MB
    char* base = ws + (size_t)nspl * SPLIT_BYTES;
    unsigned short* q  = (unsigned short*)(base);                    // 4 MB
    unsigned short* k  = (unsigned short*)(base + SPLIT_BYTES);      // 4 MB
    unsigned short* vt = (unsigned short*)(base + 2 * SPLIT_BYTES);  // 4 MB (tiled)
    float*          lp = (float*)(base + 3 * SPLIT_BYTES);           // nspl*64 KB
    unsigned short* wt = (unsigned short*)(base + 3 * SPLIT_BYTES
                                           + (size_t)nspl * TOTROWS * 4); // 96 KB

    wprep_kernel<<<3, 256, 0, stream>>>(Wq, Wk, Wv, wt);
    qkv_kernel<<<dim3(TOTROWS / 64, 3), 256, 0, stream>>>(
        x, wt, bq, bk, bv, q, k, vt);
    attn_kernel<<<nspl * 128, 256, 0, stream>>>(q, k, vt, opart, lp);
    combine_kernel<<<TOTROWS * 16 / 256, 256, 0, stream>>>(x, opart, lp, out, nspl);
}